// Round 5
// baseline (2515.402 us; speedup 1.0000x reference)
//
#include <hip/hip_runtime.h>

// ResidualQuantizer: 3-level RVQ, all heavy dot products on the MATRIX pipe.
// Levels 0/1 argmin + level-2 minmax: bf16 3-way error-compensated split
//   (x = b1+b2+b3, 6 MFMAs keep all terms >= 2^-27) -> fp32-dot-class accuracy.
//   argmin trick: score = cross - c2/2 (C-init = -c2/2), r2 drops out.
// Level 2 = 50-iter Sinkhorn in potential form (exp2 domain):
//   vt = twot*cross + w ; sigma_j = sum_i 2^(vt - rowLSE2_i) ; w += log2(B/K) - log2 sigma
//   fp16 2-split 4-MFMA scores (as R4, passed); online 2-chunk softmax per wave
//   (full 256-col row ownership, no inner barriers).
// codes2: bf16 3-split argmax on twot-scaled planes. sigma: u64 fixed-point atomics.

#define BSZ   262144
#define DIM   32
#define KK    256
#define CHUNK 128
#define NBLK  (BSZ / CHUNK)    // 2048 (stageA, fcodes)
#define NIBLK (BSZ / 256)      // 1024 (iter, fout)
#define LROW  36
#define SKEPS 0.003f
#define NIT   50

// ws float offsets
#define WS_SSQ  0
#define WS_MINK 1
#define WS_MAXK 2
#define WS_TWOT 3
#define WS_W0   256
#define WS_WA   512
#define WS_C2   1024   // c2/2 per level: 3*256 floats
// byte offsets
#define WSB_SIG 8192   // 3*256 u64
#define WSB_BH  16384  // fp16 hi plane (iter), 16KB
#define WSB_BL  32768  // fp16 lo plane, 16KB
#define WSB_QB  49152  // bf16 planes: 12 x 1024 uint4 (lvl0,1,2 x3; twot-scaled cb2 x3)

// d_out float offsets
#define OC0   0
#define OC1   BSZ
#define OC2   (2 * BSZ)
#define OQ    (3 * BSZ)
#define OLOSS (3 * BSZ + BSZ * DIM)
#define OU_AH (3u * BSZ)
#define OU_AL (3u * BSZ + 4194304u)

typedef short short8 __attribute__((ext_vector_type(8)));
typedef _Float16 half8 __attribute__((ext_vector_type(8)));
typedef float f32x4 __attribute__((ext_vector_type(4)));

#if __has_builtin(__builtin_amdgcn_exp2f)
#define EXP2(x) __builtin_amdgcn_exp2f(x)
#else
#define EXP2(x) exp2f(x)
#endif

#if __has_builtin(__builtin_amdgcn_update_dpp)
#define ROR16(x, N)                                                            \
  __int_as_float(__builtin_amdgcn_update_dpp(__float_as_int(x),                \
                 __float_as_int(x), 0x120 + (N), 0xF, 0xF, false))
#define ROR16I(x, N) __builtin_amdgcn_update_dpp((x), (x), 0x120 + (N), 0xF, 0xF, false)
#else
#define ROR16(x, N) __shfl_xor((x), (N))
#define ROR16I(x, N) __shfl_xor((x), (N))
#endif

__device__ __forceinline__ float wred_max(float x) {
  x = fmaxf(x, ROR16(x, 1)); x = fmaxf(x, ROR16(x, 2));
  x = fmaxf(x, ROR16(x, 4)); x = fmaxf(x, ROR16(x, 8));
  x = fmaxf(x, __shfl_xor(x, 16)); x = fmaxf(x, __shfl_xor(x, 32));
  return x;
}
__device__ __forceinline__ float wred_min(float x) {
  x = fminf(x, ROR16(x, 1)); x = fminf(x, ROR16(x, 2));
  x = fminf(x, ROR16(x, 4)); x = fminf(x, ROR16(x, 8));
  x = fminf(x, __shfl_xor(x, 16)); x = fminf(x, __shfl_xor(x, 32));
  return x;
}
__device__ __forceinline__ float wred_sum(float x) {
  x += ROR16(x, 1); x += ROR16(x, 2); x += ROR16(x, 4); x += ROR16(x, 8);
  x += __shfl_xor(x, 16); x += __shfl_xor(x, 32);
  return x;
}
__device__ __forceinline__ float g16_max(float x) {
  x = fmaxf(x, ROR16(x, 1)); x = fmaxf(x, ROR16(x, 2));
  x = fmaxf(x, ROR16(x, 4)); x = fmaxf(x, ROR16(x, 8));
  return x;
}
__device__ __forceinline__ float g16_sum(float x) {
  x += ROR16(x, 1); x += ROR16(x, 2); x += ROR16(x, 4); x += ROR16(x, 8);
  return x;
}
// argmax over the 16-lane group; tie -> lower index (np first-occurrence)
__device__ __forceinline__ void g16_argmax(float& v, int& j) {
  { float ov = ROR16(v,1); int oj = ROR16I(j,1); if (ov > v || (ov == v && oj < j)) { v = ov; j = oj; } }
  { float ov = ROR16(v,2); int oj = ROR16I(j,2); if (ov > v || (ov == v && oj < j)) { v = ov; j = oj; } }
  { float ov = ROR16(v,4); int oj = ROR16I(j,4); if (ov > v || (ov == v && oj < j)) { v = ov; j = oj; } }
  { float ov = ROR16(v,8); int oj = ROR16I(j,8); if (ov > v || (ov == v && oj < j)) { v = ov; j = oj; } }
}

__device__ __forceinline__ unsigned fkey(float f) {
  unsigned b = __float_as_uint(f);
  return (b & 0x80000000u) ? ~b : (b | 0x80000000u);
}
__device__ __forceinline__ float fkeyinv(unsigned k) {
  return __uint_as_float((k & 0x80000000u) ? (k ^ 0x80000000u) : ~k);
}
__device__ __forceinline__ unsigned pk2h(_Float16 a, _Float16 b) {
  unsigned short ua = __builtin_bit_cast(unsigned short, a);
  unsigned short ub = __builtin_bit_cast(unsigned short, b);
  return (unsigned)ua | ((unsigned)ub << 16);
}
__device__ __forceinline__ unsigned short bf16rne(float x) {
  unsigned u = __float_as_uint(x);
  return (unsigned short)((u + 0x7FFFu + ((u >> 16) & 1u)) >> 16);
}
__device__ __forceinline__ float bf2f(unsigned short h) {
  return __uint_as_float(((unsigned)h) << 16);
}
__device__ __forceinline__ void split3_8(const float* xs, short8& a1, short8& a2, short8& a3) {
#pragma unroll
  for (int u = 0; u < 8; ++u) {
    float x = xs[u];
    unsigned short b1 = bf16rne(x); x -= bf2f(b1);
    unsigned short b2 = bf16rne(x); x -= bf2f(b2);
    unsigned short b3 = bf16rne(x);
    a1[u] = (short)b1; a2[u] = (short)b2; a3[u] = (short)b3;
  }
}
// 6-term error-compensated product (smallest terms first)
__device__ __forceinline__ f32x4 mfma6(short8 A1, short8 A2, short8 A3,
                                       const uint4* __restrict__ q1,
                                       const uint4* __restrict__ q2,
                                       const uint4* __restrict__ q3,
                                       int idx, f32x4 acc) {
  short8 B1 = __builtin_bit_cast(short8, q1[idx]);
  short8 B2 = __builtin_bit_cast(short8, q2[idx]);
  short8 B3 = __builtin_bit_cast(short8, q3[idx]);
  acc = __builtin_amdgcn_mfma_f32_16x16x32_bf16(A3, B1, acc, 0, 0, 0);
  acc = __builtin_amdgcn_mfma_f32_16x16x32_bf16(A1, B3, acc, 0, 0, 0);
  acc = __builtin_amdgcn_mfma_f32_16x16x32_bf16(A2, B2, acc, 0, 0, 0);
  acc = __builtin_amdgcn_mfma_f32_16x16x32_bf16(A2, B1, acc, 0, 0, 0);
  acc = __builtin_amdgcn_mfma_f32_16x16x32_bf16(A1, B2, acc, 0, 0, 0);
  acc = __builtin_amdgcn_mfma_f32_16x16x32_bf16(A1, B1, acc, 0, 0, 0);
  return acc;
}
// build this lane's bf16 3-split A fragment from LDS row tile
__device__ __forceinline__ void build_a(const float* zl, int b, int lane,
                                        short8& A1, short8& A2, short8& A3) {
  int row = b * 16 + (lane & 15);
  int kb = (lane >> 4) * 8;
  float xs[8];
  float4 t0 = *reinterpret_cast<const float4*>(&zl[row * LROW + kb]);
  float4 t1 = *reinterpret_cast<const float4*>(&zl[row * LROW + kb + 4]);
  xs[0]=t0.x; xs[1]=t0.y; xs[2]=t0.z; xs[3]=t0.w;
  xs[4]=t1.x; xs[5]=t1.y; xs[6]=t1.z; xs[7]=t1.w;
  split3_8(xs, A1, A2, A3);
}

// ---------------- prep0: init + c2/2 + bf16 3-split B planes for cb0/1/2 ----
__global__ void prep0_k(const float* __restrict__ cb0, const float* __restrict__ cb1,
                        const float* __restrict__ cb2, unsigned* __restrict__ wsu,
                        float* __restrict__ wsf, uint4* __restrict__ qb,
                        unsigned long long* __restrict__ sig0) {
  int t = threadIdx.x;
  sig0[t] = 0ull;
  if (t == 0) { wsu[WS_SSQ] = 0u; wsu[WS_MINK] = 0xFFFFFFFFu; wsu[WS_MAXK] = 0u; }
  const float* cbs[3] = {cb0, cb1, cb2};
  for (int lvl = 0; lvl < 3; ++lvl) {
    const float* cb = cbs[lvl];
    float s = 0.f;
#pragma unroll
    for (int d = 0; d < DIM; ++d) { float c = cb[t * DIM + d]; s = fmaf(c, c, s); }
    wsf[WS_C2 + lvl * 256 + t] = 0.5f * s;
    for (int g = 0; g < 4; ++g) {
      int slot = g * 256 + t;
      int jt = slot >> 6, l = slot & 63;
      int col = jt * 16 + (l & 15), kb = (l >> 4) * 8;
      float xs[8];
#pragma unroll
      for (int u = 0; u < 8; ++u) xs[u] = cb[col * DIM + kb + u];
      short8 b1, b2, b3;
      split3_8(xs, b1, b2, b3);
      qb[(lvl * 3 + 0) * 1024 + slot] = __builtin_bit_cast(uint4, b1);
      qb[(lvl * 3 + 1) * 1024 + slot] = __builtin_bit_cast(uint4, b2);
      qb[(lvl * 3 + 2) * 1024 + slot] = __builtin_bit_cast(uint4, b3);
    }
  }
}

// ---------------- stageA helpers -------------------------------------------
__device__ __forceinline__ void argmin_mfma(const uint4* __restrict__ q1,
                                            const uint4* __restrict__ q2,
                                            const uint4* __restrict__ q3,
                                            const float* __restrict__ c2p,
                                            const float* zl, int* codel,
                                            int lane, int wid) {
  float c2h[16];
#pragma unroll
  for (int jt = 0; jt < 16; ++jt) c2h[jt] = c2p[jt * 16 + (lane & 15)];
  for (int bb = 0; bb < 2; ++bb) {
    int b = wid * 2 + bb;
    short8 A1, A2, A3;
    build_a(zl, b, lane, A1, A2, A3);
    float bv[4] = {-3.4e38f, -3.4e38f, -3.4e38f, -3.4e38f};
    int bj[4] = {0, 0, 0, 0};
    for (int jt = 0; jt < 16; ++jt) {
      f32x4 acc = {-c2h[jt], -c2h[jt], -c2h[jt], -c2h[jt]};
      acc = mfma6(A1, A2, A3, q1, q2, q3, jt * 64 + lane, acc);
      int col = jt * 16 + (lane & 15);
#pragma unroll
      for (int r = 0; r < 4; ++r)
        if (acc[r] > bv[r]) { bv[r] = acc[r]; bj[r] = col; }  // strict > keeps first jt
    }
#pragma unroll
    for (int r = 0; r < 4; ++r) g16_argmax(bv[r], bj[r]);
    if ((lane & 15) == 0) {
#pragma unroll
      for (int r = 0; r < 4; ++r) codel[b * 16 + (lane >> 4) * 4 + r] = bj[r];
    }
  }
}

// zl[row] -= cb[code[row]] on this thread's half-row; returns local sum of squares
__device__ __forceinline__ float remap_phase(const float* __restrict__ cb, float* zl,
                                             const int* codel, int tid) {
  int row = tid & (CHUNK - 1);
  int half = tid >> 7;
  const float4* cbg = reinterpret_cast<const float4*>(cb + codel[row] * DIM + half * 16);
  float4* zr = reinterpret_cast<float4*>(&zl[row * LROW + half * 16]);
  float local = 0.f;
#pragma unroll
  for (int k = 0; k < 4; ++k) {
    float4 cv = cbg[k];
    float4 v = zr[k];
    v.x -= cv.x; v.y -= cv.y; v.z -= cv.z; v.w -= cv.w;
    zr[k] = v;
    local = fmaf(v.x, v.x, local); local = fmaf(v.y, v.y, local);
    local = fmaf(v.z, v.z, local); local = fmaf(v.w, v.w, local);
  }
  return local;
}

__global__ __launch_bounds__(256, 2) void stageA_k(const float* __restrict__ z,
                                                   const float* __restrict__ cb0,
                                                   const float* __restrict__ cb1,
                                                   float* __restrict__ out,
                                                   unsigned* __restrict__ outu,
                                                   unsigned* __restrict__ wsu,
                                                   float* __restrict__ wsf,
                                                   const uint4* __restrict__ qb) {
  __shared__ float zl[CHUNK * LROW];
  __shared__ float rsq[CHUNK];
  __shared__ int codel[CHUNK];
  __shared__ float red[4];
  const int tid = threadIdx.x, lane = tid & 63, wid = tid >> 6;
  const long base = (long)blockIdx.x * CHUNK;

#pragma unroll
  for (int g = 0; g < 4; ++g) {
    int f4 = g * 256 + tid;
    float4 v = reinterpret_cast<const float4*>(z + base * DIM)[f4];
    int row = f4 >> 3, d = (f4 & 7) * 4;
    *reinterpret_cast<float4*>(&zl[row * LROW + d]) = v;
  }
  __syncthreads();

  float loss_acc = 0.f;

  // ---- level 0
  argmin_mfma(qb + 0 * 1024, qb + 1 * 1024, qb + 2 * 1024, wsf + WS_C2, zl, codel, lane, wid);
  __syncthreads();
  if (tid < CHUNK) out[OC0 + base + tid] = (float)codel[tid];
  loss_acc += remap_phase(cb0, zl, codel, tid);
  __syncthreads();

  // ---- level 1
  argmin_mfma(qb + 3 * 1024, qb + 4 * 1024, qb + 5 * 1024, wsf + WS_C2 + 256, zl, codel, lane, wid);
  __syncthreads();
  if (tid < CHUNK) out[OC1 + base + tid] = (float)codel[tid];
  loss_acc += remap_phase(cb1, zl, codel, tid);
  __syncthreads();

  // r2 squared norms (needed by minmax only)
  if (tid < CHUNK) {
    float s = 0.f;
#pragma unroll
    for (int d = 0; d < DIM; ++d) { float x = zl[tid * LROW + d]; s = fmaf(x, x, s); }
    rsq[tid] = s;
  }
  __syncthreads();

  // ---- level 2 global min/max of distances: d = r2 - 2*(cross - c2/2)
  {
    const uint4* q1 = qb + 6 * 1024;
    const uint4* q2 = qb + 7 * 1024;
    const uint4* q3 = qb + 8 * 1024;
    const float* c2p = wsf + WS_C2 + 512;
    float c2h[16];
#pragma unroll
    for (int jt = 0; jt < 16; ++jt) c2h[jt] = c2p[jt * 16 + (lane & 15)];
    float dmn = 3.4e38f, dmx = -3.4e38f;
    for (int bb = 0; bb < 2; ++bb) {
      int b = wid * 2 + bb;
      short8 A1, A2, A3;
      build_a(zl, b, lane, A1, A2, A3);
      float mn[4] = {3.4e38f, 3.4e38f, 3.4e38f, 3.4e38f};
      float mx[4] = {-3.4e38f, -3.4e38f, -3.4e38f, -3.4e38f};
      for (int jt = 0; jt < 16; ++jt) {
        f32x4 acc = {-c2h[jt], -c2h[jt], -c2h[jt], -c2h[jt]};
        acc = mfma6(A1, A2, A3, q1, q2, q3, jt * 64 + lane, acc);
#pragma unroll
        for (int r = 0; r < 4; ++r) { mn[r] = fminf(mn[r], acc[r]); mx[r] = fmaxf(mx[r], acc[r]); }
      }
#pragma unroll
      for (int r = 0; r < 4; ++r) {
        float r2 = rsq[b * 16 + (lane >> 4) * 4 + r];
        dmn = fminf(dmn, fmaf(-2.f, mx[r], r2));
        dmx = fmaxf(dmx, fmaf(-2.f, mn[r], r2));
      }
    }
    dmn = wred_min(dmn);
    dmx = wred_max(dmx);
    if (lane == 0) {
      atomicMin(&wsu[WS_MINK], fkey(dmn));
      atomicMax(&wsu[WS_MAXK], fkey(dmx));
    }
  }

  // ---- export r2 as fp16 hi/lo A-fragment planes (k-map: k = (l>>4)*8 + u*2)
#pragma unroll
  for (int g2 = 0; g2 < 8; ++g2) {
    int slot = g2 * 256 + tid;
    int b = slot >> 8;
    int l = (slot >> 2) & 63;
    int u = slot & 3;
    int row = b * 16 + (l & 15);
    int k = (l >> 4) * 8 + u * 2;
    float x0 = zl[row * LROW + k], x1 = zl[row * LROW + k + 1];
    _Float16 h0 = (_Float16)x0, h1 = (_Float16)x1;
    _Float16 q0 = (_Float16)(x0 - (float)h0), q1 = (_Float16)(x1 - (float)h1);
    unsigned gbase = ((unsigned)blockIdx.x * 8u + (unsigned)b) * 256u + (unsigned)(l * 4 + u);
    outu[OU_AH + gbase] = pk2h(h0, h1);
    outu[OU_AL + gbase] = pk2h(q0, q1);
  }

  loss_acc = wred_sum(loss_acc);
  if (lane == 0) red[wid] = loss_acc;
  __syncthreads();
  if (tid == 0) atomicAdd(&wsf[WS_SSQ], red[0] + red[1] + red[2] + red[3]);
}

// ---------------- prep: t, w0, fp16 B planes (iter), bf16 scaled planes -----
__global__ void prep_k(const float* __restrict__ cb2, unsigned* __restrict__ wsu,
                       float* __restrict__ wsf, unsigned* __restrict__ bh,
                       unsigned* __restrict__ bl, uint4* __restrict__ qb) {
  int j = threadIdx.x;  // 256 threads
  float dmin = fkeyinv(wsu[WS_MINK]);
  float dmax = fkeyinv(wsu[WS_MAXK]);
  float mid = (dmax + dmin) * 0.5f;
  float amp = fmaxf(dmax - mid, 1e-5f);
  float t = 1.0f / (amp * SKEPS);
  const float L2E = 1.4426950408889634f;
  float T2L = 2.0f * t * L2E;
  if (j == 0) wsf[WS_TWOT] = T2L;
  float s = 0.f;
#pragma unroll
  for (int d = 0; d < DIM; ++d) { float c = cb2[j * DIM + d]; s = fmaf(c, c, s); }
  wsf[WS_W0 + j] = -t * L2E * s;
  // fp16 2-split planes for iter_k (u32-granular layout; k = (l>>4)*8 + u*2)
  for (int g = 0; g < 16; ++g) {
    int slot = g * 256 + j;
    int jt = slot >> 8, l = (slot >> 2) & 63, u = slot & 3;
    int col = jt * 16 + (l & 15);
    int k = (l >> 4) * 8 + u * 2;
    float b0 = T2L * cb2[col * DIM + k], b1 = T2L * cb2[col * DIM + k + 1];
    _Float16 h0 = (_Float16)b0, h1 = (_Float16)b1;
    _Float16 q0 = (_Float16)(b0 - (float)h0), q1 = (_Float16)(b1 - (float)h1);
    bh[slot] = pk2h(h0, h1);
    bl[slot] = pk2h(q0, q1);
  }
  // bf16 3-split twot-scaled planes for fcodes (slots 9..11)
  for (int g = 0; g < 4; ++g) {
    int slot = g * 256 + j;
    int jt = slot >> 6, l = slot & 63;
    int col = jt * 16 + (l & 15), kb = (l >> 4) * 8;
    float xs[8];
#pragma unroll
    for (int u = 0; u < 8; ++u) xs[u] = T2L * cb2[col * DIM + kb + u];
    short8 b1v, b2v, b3v;
    split3_8(xs, b1v, b2v, b3v);
    qb[9 * 1024 + slot]  = __builtin_bit_cast(uint4, b1v);
    qb[10 * 1024 + slot] = __builtin_bit_cast(uint4, b2v);
    qb[11 * 1024 + slot] = __builtin_bit_cast(uint4, b3v);
  }
}

// ---------------- iter: one Sinkhorn iteration ------------------------------
__global__ __launch_bounds__(256, 2) void iter_k(const uint4* __restrict__ afh,
                                                 const uint4* __restrict__ afl,
                                                 const uint4* __restrict__ bfh,
                                                 const uint4* __restrict__ bfl,
                                                 const float* __restrict__ w_rd,
                                                 float* __restrict__ w_wr,
                                                 const unsigned long long* __restrict__ s_rd,
                                                 unsigned long long* __restrict__ s_wr,
                                                 unsigned long long* __restrict__ s_zr,
                                                 int first) {
  __shared__ float wsh[KK];
  __shared__ float ssh[4][KK];
  const int tid = threadIdx.x, lane = tid & 63, wv = tid >> 6;

  {
    float wj = first ? w_rd[tid]
                     : w_rd[tid] + 34.0f - log2f(fmaxf((float)s_rd[tid], 1.0f));
    wsh[tid] = wj;
    if (blockIdx.x == 0) { w_wr[tid] = wj; s_zr[tid] = 0ull; }
  }
  __syncthreads();
  float wc[16];
#pragma unroll
  for (int jt = 0; jt < 16; ++jt) wc[jt] = wsh[jt * 16 + (lane & 15)];

  float sg[16];
#pragma unroll
  for (int jt = 0; jt < 16; ++jt) sg[jt] = 0.f;

  for (int bb = 0; bb < 4; ++bb) {
    const int batchid = blockIdx.x * 16 + wv * 4 + bb;
    half8 Ah = __builtin_bit_cast(half8, afh[batchid * 64 + lane]);
    half8 Al = __builtin_bit_cast(half8, afl[batchid * 64 + lane]);
    f32x4 p1[8], p2[8];
    float m1[4], s1[4], m2[4], s2[4];
    // chunk 0: col tiles 0..7
#pragma unroll
    for (int j = 0; j < 8; ++j) {
      half8 Bh = __builtin_bit_cast(half8, bfh[j * 64 + lane]);
      half8 Bl = __builtin_bit_cast(half8, bfl[j * 64 + lane]);
      f32x4 acc = {0.f, 0.f, 0.f, 0.f};
      acc = __builtin_amdgcn_mfma_f32_16x16x32_f16(Al, Bl, acc, 0, 0, 0);
      acc = __builtin_amdgcn_mfma_f32_16x16x32_f16(Al, Bh, acc, 0, 0, 0);
      acc = __builtin_amdgcn_mfma_f32_16x16x32_f16(Ah, Bl, acc, 0, 0, 0);
      acc = __builtin_amdgcn_mfma_f32_16x16x32_f16(Ah, Bh, acc, 0, 0, 0);
#pragma unroll
      for (int r = 0; r < 4; ++r) acc[r] += wc[j];
      p1[j] = acc;
    }
#pragma unroll
    for (int r = 0; r < 4; ++r) {
      float a = fmaxf(fmaxf(p1[0][r], p1[1][r]), fmaxf(p1[2][r], p1[3][r]));
      float b = fmaxf(fmaxf(p1[4][r], p1[5][r]), fmaxf(p1[6][r], p1[7][r]));
      m1[r] = g16_max(fmaxf(a, b));
    }
#pragma unroll
    for (int r = 0; r < 4; ++r) {
#pragma unroll
      for (int j = 0; j < 8; ++j) p1[j][r] = EXP2(p1[j][r] - m1[r]);
      float a = (p1[0][r] + p1[1][r]) + (p1[2][r] + p1[3][r]);
      float b = (p1[4][r] + p1[5][r]) + (p1[6][r] + p1[7][r]);
      s1[r] = g16_sum(a + b);
    }
    // chunk 1: col tiles 8..15
#pragma unroll
    for (int j = 0; j < 8; ++j) {
      half8 Bh = __builtin_bit_cast(half8, bfh[(8 + j) * 64 + lane]);
      half8 Bl = __builtin_bit_cast(half8, bfl[(8 + j) * 64 + lane]);
      f32x4 acc = {0.f, 0.f, 0.f, 0.f};
      acc = __builtin_amdgcn_mfma_f32_16x16x32_f16(Al, Bl, acc, 0, 0, 0);
      acc = __builtin_amdgcn_mfma_f32_16x16x32_f16(Al, Bh, acc, 0, 0, 0);
      acc = __builtin_amdgcn_mfma_f32_16x16x32_f16(Ah, Bl, acc, 0, 0, 0);
      acc = __builtin_amdgcn_mfma_f32_16x16x32_f16(Ah, Bh, acc, 0, 0, 0);
#pragma unroll
      for (int r = 0; r < 4; ++r) acc[r] += wc[8 + j];
      p2[j] = acc;
    }
#pragma unroll
    for (int r = 0; r < 4; ++r) {
      float a = fmaxf(fmaxf(p2[0][r], p2[1][r]), fmaxf(p2[2][r], p2[3][r]));
      float b = fmaxf(fmaxf(p2[4][r], p2[5][r]), fmaxf(p2[6][r], p2[7][r]));
      m2[r] = g16_max(fmaxf(a, b));
    }
#pragma unroll
    for (int r = 0; r < 4; ++r) {
#pragma unroll
      for (int j = 0; j < 8; ++j) p2[j][r] = EXP2(p2[j][r] - m2[r]);
      float a = (p2[0][r] + p2[1][r]) + (p2[2][r] + p2[3][r]);
      float b = (p2[4][r] + p2[5][r]) + (p2[6][r] + p2[7][r]);
      s2[r] = g16_sum(a + b);
    }
    // online combine + sigma accumulate
#pragma unroll
    for (int r = 0; r < 4; ++r) {
      float M = fmaxf(m1[r], m2[r]);
      float f1 = EXP2(m1[r] - M), f2 = EXP2(m2[r] - M);
      float tot = fmaf(s1[r], f1, s2[r] * f2);
      float it = __builtin_amdgcn_rcpf(tot);
      float r1 = f1 * it, r2v = f2 * it;
#pragma unroll
      for (int j = 0; j < 8; ++j) {
        sg[j]     = fmaf(p1[j][r], r1,  sg[j]);
        sg[8 + j] = fmaf(p2[j][r], r2v, sg[8 + j]);
      }
    }
  }
  // same-column lanes: l, l^16, l^32, l^48
#pragma unroll
  for (int jt = 0; jt < 16; ++jt) {
    float x = sg[jt];
    x += __shfl_xor(x, 16); x += __shfl_xor(x, 32);
    sg[jt] = x;
  }
  if (lane < 16) {
#pragma unroll
    for (int jt = 0; jt < 16; ++jt) ssh[wv][jt * 16 + lane] = sg[jt];
  }
  __syncthreads();
  float s = ssh[0][tid] + ssh[1][tid] + ssh[2][tid] + ssh[3][tid];
  atomicAdd(&s_wr[tid], (unsigned long long)fmaf(s, 16777216.0f, 0.5f));
}

// ---------------- fcodes: final argmax -> codes2 ---------------------------
__global__ __launch_bounds__(256, 2) void fcodes_k(const float* __restrict__ z,
                                                   const float* __restrict__ cb0,
                                                   const float* __restrict__ cb1,
                                                   float* __restrict__ out,
                                                   const uint4* __restrict__ qb,
                                                   const float* __restrict__ w_rd,
                                                   const unsigned long long* __restrict__ s_rd) {
  __shared__ float zl[CHUNK * LROW];
  __shared__ float wsh[KK];
  __shared__ int codel[CHUNK];
  const int tid = threadIdx.x, lane = tid & 63, wid = tid >> 6;
  const long base = (long)blockIdx.x * CHUNK;

  wsh[tid] = w_rd[tid] + 34.0f - log2f(fmaxf((float)s_rd[tid], 1.0f));
#pragma unroll
  for (int g = 0; g < 4; ++g) {
    int f4 = g * 256 + tid;
    float4 v = reinterpret_cast<const float4*>(z + base * DIM)[f4];
    int row = f4 >> 3, d = (f4 & 7) * 4;
    *reinterpret_cast<float4*>(&zl[row * LROW + d]) = v;
  }
  __syncthreads();
  // r2 = z - cb0[c0] - cb1[c1] (bit-exact vs stageA remap sequence)
  {
    int row = tid & (CHUNK - 1);
    int half = tid >> 7;
    int c0 = (int)out[OC0 + base + row];
    int c1 = (int)out[OC1 + base + row];
    const float4* e0 = reinterpret_cast<const float4*>(cb0 + c0 * DIM + half * 16);
    const float4* e1 = reinterpret_cast<const float4*>(cb1 + c1 * DIM + half * 16);
    float4* zr = reinterpret_cast<float4*>(&zl[row * LROW + half * 16]);
#pragma unroll
    for (int k = 0; k < 4; ++k) {
      float4 a = e0[k], bb = e1[k], v = zr[k];
      v.x = (v.x - a.x) - bb.x; v.y = (v.y - a.y) - bb.y;
      v.z = (v.z - a.z) - bb.z; v.w = (v.w - a.w) - bb.w;
      zr[k] = v;
    }
  }
  __syncthreads();

  const uint4* q1 = qb + 9 * 1024;
  const uint4* q2 = qb + 10 * 1024;
  const uint4* q3 = qb + 11 * 1024;
  float wc[16];
#pragma unroll
  for (int jt = 0; jt < 16; ++jt) wc[jt] = wsh[jt * 16 + (lane & 15)];
  for (int bb = 0; bb < 2; ++bb) {
    int b = wid * 2 + bb;
    short8 A1, A2, A3;
    build_a(zl, b, lane, A1, A2, A3);
    float bv[4] = {-3.4e38f, -3.4e38f, -3.4e38f, -3.4e38f};
    int bj[4] = {0, 0, 0, 0};
    for (int jt = 0; jt < 16; ++jt) {
      f32x4 acc = {wc[jt], wc[jt], wc[jt], wc[jt]};
      acc = mfma6(A1, A2, A3, q1, q2, q3, jt * 64 + lane, acc);
      int col = jt * 16 + (lane & 15);
#pragma unroll
      for (int r = 0; r < 4; ++r)
        if (acc[r] > bv[r]) { bv[r] = acc[r]; bj[r] = col; }
    }
#pragma unroll
    for (int r = 0; r < 4; ++r) g16_argmax(bv[r], bj[r]);
    if ((lane & 15) == 0) {
#pragma unroll
      for (int r = 0; r < 4; ++r) codel[b * 16 + (lane >> 4) * 4 + r] = bj[r];
    }
  }
  __syncthreads();
  if (tid < CHUNK) out[OC2 + base + tid] = (float)codel[tid];
}

// ---------------- fout: quantized = e0+e1+e2, level-2 loss ------------------
__global__ __launch_bounds__(256) void fout_k(const float* __restrict__ z,
                                              const float* __restrict__ cb0,
                                              const float* __restrict__ cb1,
                                              const float* __restrict__ cb2,
                                              float* __restrict__ out,
                                              float* __restrict__ wsf) {
  __shared__ int cc0[256], cc1[256], cc2[256];
  __shared__ float red[4];
  const int tid = threadIdx.x, lane = tid & 63, wv = tid >> 6;
  const long rbase = (long)blockIdx.x * 256;
  cc0[tid] = (int)out[OC0 + rbase + tid];
  cc1[tid] = (int)out[OC1 + rbase + tid];
  cc2[tid] = (int)out[OC2 + rbase + tid];
  __syncthreads();
  float loss = 0.f;
#pragma unroll
  for (int g = 0; g < 8; ++g) {
    long f4 = (long)blockIdx.x * 2048 + g * 256 + tid;
    int lrow = (g * 256 + tid) >> 3;
    int d4 = (g * 256 + tid) & 7;
    float4 zv = reinterpret_cast<const float4*>(z)[f4];
    float4 e0 = *reinterpret_cast<const float4*>(&cb0[cc0[lrow] * DIM + d4 * 4]);
    float4 e1 = *reinterpret_cast<const float4*>(&cb1[cc1[lrow] * DIM + d4 * 4]);
    float4 e2 = *reinterpret_cast<const float4*>(&cb2[cc2[lrow] * DIM + d4 * 4]);
    float4 q;
    q.x = (e0.x + e1.x) + e2.x; q.y = (e0.y + e1.y) + e2.y;
    q.z = (e0.z + e1.z) + e2.z; q.w = (e0.w + e1.w) + e2.w;
    reinterpret_cast<float4*>(out + OQ)[f4] = q;
    float rx = ((zv.x - e0.x) - e1.x) - e2.x;
    float ry = ((zv.y - e0.y) - e1.y) - e2.y;
    float rz = ((zv.z - e0.z) - e1.z) - e2.z;
    float rw = ((zv.w - e0.w) - e1.w) - e2.w;
    loss = fmaf(rx, rx, loss); loss = fmaf(ry, ry, loss);
    loss = fmaf(rz, rz, loss); loss = fmaf(rw, rw, loss);
  }
  loss = wred_sum(loss);
  if (lane == 0) red[wv] = loss;
  __syncthreads();
  if (tid == 0) atomicAdd(&wsf[WS_SSQ], red[0] + red[1] + red[2] + red[3]);
}

__global__ void losswrite_k(float* __restrict__ out, const float* __restrict__ wsf) {
  if (threadIdx.x == 0) out[OLOSS] = 1.25f * wsf[WS_SSQ] / 8388608.0f;
}

extern "C" void kernel_launch(void* const* d_in, const int* in_sizes, int n_in,
                              void* d_out, int out_size, void* d_ws, size_t ws_size,
                              hipStream_t stream) {
  const float* z   = (const float*)d_in[0];
  const float* cb0 = (const float*)d_in[1];
  const float* cb1 = (const float*)d_in[2];
  const float* cb2 = (const float*)d_in[3];
  float* out = (float*)d_out;
  unsigned* outu = (unsigned*)d_out;
  float* wsf = (float*)d_ws;
  unsigned* wsu = (unsigned*)d_ws;
  unsigned long long* sig = (unsigned long long*)((char*)d_ws + WSB_SIG);
  unsigned* bh = (unsigned*)((char*)d_ws + WSB_BH);
  unsigned* bl = (unsigned*)((char*)d_ws + WSB_BL);
  uint4* qb = (uint4*)((char*)d_ws + WSB_QB);

  const uint4* afh = (const uint4*)(outu + OU_AH);
  const uint4* afl = (const uint4*)(outu + OU_AL);
  const uint4* bfh = (const uint4*)bh;
  const uint4* bfl = (const uint4*)bl;

  prep0_k<<<1, 256, 0, stream>>>(cb0, cb1, cb2, wsu, wsf, qb, sig);
  stageA_k<<<NBLK, 256, 0, stream>>>(z, cb0, cb1, out, outu, wsu, wsf, qb);
  prep_k<<<1, 256, 0, stream>>>(cb2, wsu, wsf, bh, bl, qb);
  for (int it = 0; it < NIT; ++it) {
    const float* w_rd = (it == 0) ? (wsf + WS_W0) : (wsf + WS_WA + ((it - 1) & 1) * KK);
    float* w_wr = wsf + WS_WA + (it & 1) * KK;
    const unsigned long long* s_rd = sig + KK * ((it + 2) % 3);
    unsigned long long* s_wr = sig + KK * (it % 3);
    unsigned long long* s_zr = sig + KK * ((it + 1) % 3);
    iter_k<<<NIBLK, 256, 0, stream>>>(afh, afl, bfh, bfl, w_rd, w_wr, s_rd, s_wr, s_zr,
                                      it == 0 ? 1 : 0);
  }
  fcodes_k<<<NBLK, 256, 0, stream>>>(z, cb0, cb1, out, qb,
                                     wsf + WS_WA + ((NIT - 1) & 1) * KK,
                                     sig + KK * ((NIT - 1) % 3));
  fout_k<<<NIBLK, 256, 0, stream>>>(z, cb0, cb1, cb2, out, wsf);
  losswrite_k<<<1, 64, 0, stream>>>(out, wsf);
}